// Round 19
// baseline (259.334 us; speedup 1.0000x reference)
//
#include <hip/hip_runtime.h>
#include <stdint.h>

#define NN 100000
#define NE 1600000
#define NR 4
#define FD 128
#define KA 512            // layer-2 A matrix cols (rel blocks only)
#define KT 640
#define NQ 1024
#define HIDN 256

#define MPAD 100096                    // NN rounded up to 128
#define NCHK (MPAD / 128)              // 782 row-chunks per Y table
#define NBE ((NE + 2047) / 2048)       // 782 edge-scan blocks
#define NCHB ((NN + 255) / 256)        // 391 bitmap chunks
#define MAXS 49152                     // upper bound on |S| (expected ~30k)
#define NCH1 (MAXS / 256)              // 192
#define MAXL2 65536                    // upper bound on layer-2 edges (expected ~33k)

using u16 = unsigned short;
using u32 = unsigned int;
using u8 = unsigned char;
typedef __attribute__((ext_vector_type(8))) __bf16 bf16x8;
typedef __attribute__((ext_vector_type(4))) float f32x4;

__device__ __forceinline__ u16 f2b(float f) {
    u32 u = __builtin_bit_cast(u32, f);
    u32 r = u + 0x7FFFu + ((u >> 16) & 1u);   // round-to-nearest-even
    return (u16)(r >> 16);
}
__device__ __forceinline__ float b2f_lo(u32 v) { return __builtin_bit_cast(float, v << 16); }
__device__ __forceinline__ float b2f_hi(u32 v) { return __builtin_bit_cast(float, v & 0xFFFF0000u); }
__device__ __forceinline__ u32 pack2(float a, float b) {
    return (u32)f2b(a) | ((u32)f2b(b) << 16);
}
__device__ __forceinline__ void gload_lds16(const void* g, void* l) {
    __builtin_amdgcn_global_load_lds((const __attribute__((address_space(1))) u32*)g,
                                     (__attribute__((address_space(3))) u32*)l, 16, 0, 0);
}

// ---------- mark query nodes ----------
__global__ __launch_bounds__(256) void mark_T(const int* __restrict__ nest,
                                              const int* __restrict__ food,
                                              u8* __restrict__ bmT, u8* __restrict__ bmS) {
    int i = blockIdx.x * 256 + threadIdx.x;
    if (i < NQ)          { int q = nest[i];      bmT[q] = 1; bmS[q] = 1; }
    else if (i < 2 * NQ) { int q = food[i - NQ]; bmT[q] = 1; bmS[q] = 1; }
}

// ---------- filter layer-2 edges (dst in T); mark their sources in S ----------
__global__ __launch_bounds__(256) void filter_l2(const int* __restrict__ ei,
                                                 const int* __restrict__ et,
                                                 const u8* __restrict__ bmT,
                                                 u8* __restrict__ bmS,
                                                 int* __restrict__ cnts,
                                                 u32* __restrict__ l2a,
                                                 u32* __restrict__ l2d) {
    __shared__ int lcnt, lbase;
    __shared__ u32 ba[2048], bd[2048];
    int t = threadIdx.x;
    if (t == 0) lcnt = 0;
    __syncthreads();
    int e0 = blockIdx.x * 2048;
    for (int j = 0; j < 8; ++j) {
        int e = e0 + j * 256 + t;
        if (e < NE) {
            int dst = ei[NE + e];
            if (bmT[dst]) {
                int src = ei[e];
                int r = et[e];
                int pos = atomicAdd(&lcnt, 1);
                ba[pos] = (u32)src | ((u32)r << 17);
                bd[pos] = (u32)dst;
                bmS[src] = 1;
            }
        }
    }
    __syncthreads();
    if (t == 0) lbase = atomicAdd(&cnts[2], lcnt);
    __syncthreads();
    for (int i = t; i < lcnt; i += 256) {
        l2a[lbase + i] = ba[i];
        l2d[lbase + i] = bd[i];
    }
}

// ---------- compact S/T ids ----------
__global__ __launch_bounds__(256) void bm_chunk(const u8* __restrict__ bmS,
                                                const u8* __restrict__ bmT,
                                                int* __restrict__ cS, int* __restrict__ cT) {
    __shared__ int sS[256], sT[256];
    int b = blockIdx.x, t = threadIdx.x;
    int n = b * 256 + t;
    int vs = (n < NN) ? bmS[n] : 0;
    int vt = (n < NN) ? bmT[n] : 0;
    sS[t] = vs; sT[t] = vt;
    __syncthreads();
    for (int o = 128; o > 0; o >>= 1) {
        if (t < o) { sS[t] += sS[t + o]; sT[t] += sT[t + o]; }
        __syncthreads();
    }
    if (t == 0) { cS[b] = sS[0]; cT[b] = sT[0]; }
}

__global__ __launch_bounds__(512) void bm_scan(const int* __restrict__ cS,
                                               const int* __restrict__ cT,
                                               int* __restrict__ oS, int* __restrict__ oT,
                                               int* __restrict__ cnts) {
    __shared__ int sS[512], sT[512];
    int t = threadIdx.x;
    int vs = (t < NCHB) ? cS[t] : 0;
    int vt = (t < NCHB) ? cT[t] : 0;
    sS[t] = vs; sT[t] = vt;
    __syncthreads();
    for (int o = 1; o < 512; o <<= 1) {
        int a = (t >= o) ? sS[t - o] : 0;
        int c = (t >= o) ? sT[t - o] : 0;
        __syncthreads();
        sS[t] += a; sT[t] += c;
        __syncthreads();
    }
    if (t < NCHB) { oS[t] = sS[t] - vs; oT[t] = sT[t] - vt; }
    if (t == NCHB - 1) { cnts[0] = sS[t]; cnts[1] = sT[t]; }
}

__global__ __launch_bounds__(256) void bm_write(const u8* __restrict__ bmS,
                                                const u8* __restrict__ bmT,
                                                const int* __restrict__ oS,
                                                const int* __restrict__ oT,
                                                int* __restrict__ sid, int* __restrict__ tidm,
                                                int* __restrict__ snode) {
    __shared__ int sS[256], sT[256];
    int b = blockIdx.x, t = threadIdx.x;
    int n = b * 256 + t;
    int vs = (n < NN) ? bmS[n] : 0;
    int vt = (n < NN) ? bmT[n] : 0;
    sS[t] = vs; sT[t] = vt;
    __syncthreads();
    for (int o = 1; o < 256; o <<= 1) {
        int a = (t >= o) ? sS[t - o] : 0;
        int c = (t >= o) ? sT[t - o] : 0;
        __syncthreads();
        sS[t] += a; sT[t] += c;
        __syncthreads();
    }
    if (n < NN) {
        int is = oS[b] + sS[t] - vs;
        int it = oT[b] + sT[t] - vt;
        sid[n] = is;
        tidm[n] = it;
        if (vs) snode[is] = n;
    }
}

// ---------- layer-2 CSR over (tid, rel) keys ----------
__global__ __launch_bounds__(256) void l2_count(const int* __restrict__ cnts,
                                                const u32* __restrict__ l2a,
                                                const u32* __restrict__ l2d,
                                                const int* __restrict__ tidm,
                                                int* __restrict__ deg2) {
    int n = cnts[2];
    for (int i = blockIdx.x * 256 + threadIdx.x; i < n; i += gridDim.x * 256)
        atomicAdd(&deg2[tidm[l2d[i]] * 4 + ((l2a[i] >> 17) & 3)], 1);
}

__global__ __launch_bounds__(1024) void l2_scan(const int* __restrict__ deg2,
                                                int* __restrict__ offs2,
                                                int* __restrict__ cur2) {
    __shared__ int sm[1024];
    int t = threadIdx.x;
    int v[8];
    int s = 0;
    for (int j = 0; j < 8; ++j) { v[j] = deg2[t * 8 + j]; s += v[j]; }
    sm[t] = s;
    __syncthreads();
    for (int o = 1; o < 1024; o <<= 1) {
        int n = (t >= o) ? sm[t - o] : 0;
        __syncthreads();
        sm[t] += n;
        __syncthreads();
    }
    int ex = sm[t] - s;
    for (int j = 0; j < 8; ++j) { offs2[t * 8 + j] = ex; cur2[t * 8 + j] = ex; ex += v[j]; }
    if (t == 1023) offs2[8192] = ex;
}

__global__ __launch_bounds__(256) void l2_scatter(const int* __restrict__ cnts,
                                                  const u32* __restrict__ l2a,
                                                  const u32* __restrict__ l2d,
                                                  const int* __restrict__ tidm,
                                                  const int* __restrict__ sid,
                                                  int* __restrict__ cur2,
                                                  int* __restrict__ spack2) {
    int n = cnts[2];
    for (int i = blockIdx.x * 256 + threadIdx.x; i < n; i += gridDim.x * 256) {
        u32 a = l2a[i];
        int k = tidm[l2d[i]] * 4 + ((a >> 17) & 3);
        int pos = atomicAdd(&cur2[k], 1);
        spack2[pos] = sid[a & 0x1FFFFu];
    }
}

// ---------- layer-1 CSR over (sid, rel) keys, padded to x8 ----------
__global__ __launch_bounds__(256) void l1_count(const int* __restrict__ ei,
                                                const int* __restrict__ et,
                                                const u8* __restrict__ bmS,
                                                const int* __restrict__ sid,
                                                int* __restrict__ deg1) {
    int e0 = blockIdx.x * 2048;
    int t = threadIdx.x;
    for (int j = 0; j < 8; ++j) {
        int e = e0 + j * 256 + t;
        if (e < NE) {
            int dst = ei[NE + e];
            if (bmS[dst]) atomicAdd(&deg1[sid[dst] * 4 + et[e]], 1);
        }
    }
}

__global__ __launch_bounds__(256) void l1_chunk(const int* __restrict__ deg1,
                                                int* __restrict__ c1) {
    __shared__ int sm[256];
    int b = blockIdx.x, t = threadIdx.x;
    int n = b * 256 + t;
    int s = deg1[4 * n] + deg1[4 * n + 1] + deg1[4 * n + 2] + deg1[4 * n + 3];
    sm[t] = (s + 7) & ~7;
    __syncthreads();
    for (int o = 128; o > 0; o >>= 1) {
        if (t < o) sm[t] += sm[t + o];
        __syncthreads();
    }
    if (t == 0) c1[b] = sm[0];
}

__global__ __launch_bounds__(256) void l1_scan(const int* __restrict__ c1,
                                               int* __restrict__ o1) {
    __shared__ int sm[256];
    int t = threadIdx.x;
    int v = (t < NCH1) ? c1[t] : 0;
    sm[t] = v;
    __syncthreads();
    for (int o = 1; o < 256; o <<= 1) {
        int n = (t >= o) ? sm[t - o] : 0;
        __syncthreads();
        sm[t] += n;
        __syncthreads();
    }
    if (t < NCH1) o1[t] = sm[t] - v;
}

__global__ __launch_bounds__(256) void l1_write(const int* __restrict__ deg1,
                                                const int* __restrict__ o1,
                                                int* __restrict__ offs6s,
                                                int* __restrict__ cur1,
                                                int* __restrict__ spack1) {
    __shared__ int sm[256];
    int b = blockIdx.x, t = threadIdx.x;
    int n = b * 256 + t;
    int d0 = deg1[4 * n], d1 = deg1[4 * n + 1], d2 = deg1[4 * n + 2], d3 = deg1[4 * n + 3];
    int s = d0 + d1 + d2 + d3;
    int sp = (s + 7) & ~7;
    sm[t] = sp;
    __syncthreads();
    for (int o = 1; o < 256; o <<= 1) {
        int v = (t >= o) ? sm[t - o] : 0;
        __syncthreads();
        sm[t] += v;
        __syncthreads();
    }
    int e0 = o1[b] + sm[t] - sp;
    int e1 = e0 + d0, e2 = e1 + d1, e3 = e2 + d2, e4 = e3 + d3, eL = e0 + sp;
    int* o6 = offs6s + (size_t)n * 6;
    o6[0] = e0; o6[1] = e1; o6[2] = e2; o6[3] = e3; o6[4] = e4; o6[5] = eL;
    cur1[4 * n] = e0; cur1[4 * n + 1] = e1; cur1[4 * n + 2] = e2; cur1[4 * n + 3] = e3;
    for (int i = e4; i < eL; ++i) spack1[i] = 5 * NN;   // pads -> Y zero row
}

__global__ __launch_bounds__(256) void l1_scatter(const int* __restrict__ ei,
                                                  const int* __restrict__ et,
                                                  const u8* __restrict__ bmS,
                                                  const int* __restrict__ sid,
                                                  int* __restrict__ cur1,
                                                  int* __restrict__ spack1) {
    int e0 = blockIdx.x * 2048;
    int t = threadIdx.x;
    for (int j = 0; j < 8; ++j) {
        int e = e0 + j * 256 + t;
        if (e < NE) {
            int dst = ei[NE + e];
            if (bmS[dst]) {
                int r = et[e];
                int src = ei[e];
                int pos = atomicAdd(&cur1[sid[dst] * 4 + r], 1);
                spack1[pos] = r * NN + src;
            }
        }
    }
}

// ---------- conversions / weight prep ----------
__global__ __launch_bounds__(256) void cvt_bf16(const float* __restrict__ in,
                                                u16* __restrict__ outp, int n) {
    int i = blockIdx.x * 256 + threadIdx.x;
    int idx = i * 4;
    if (idx >= n) return;
    float4 v = *(const float4*)(in + idx);
    u32 lo = (u32)f2b(v.x) | ((u32)f2b(v.y) << 16);
    u32 hi = (u32)f2b(v.z) | ((u32)f2b(v.w) << 16);
    *(uint2*)(outp + idx) = make_uint2(lo, hi);
}

__global__ __launch_bounds__(256) void prep_B5(const float* __restrict__ Wrel,
                                               const float* __restrict__ Wroot,
                                               u16* __restrict__ Bt5) {
    int i = blockIdx.x * 256 + threadIdx.x;
    if (i >= 5 * FD * FD) return;
    int tb = i / (FD * FD);
    int rem = i - tb * (FD * FD);
    int o = rem / FD;
    int k = rem - o * FD;
    float v = (tb < 4) ? Wrel[(size_t)tb * FD * FD + (size_t)k * FD + o]
                       : Wroot[(size_t)k * FD + o];
    Bt5[i] = f2b(v);
}

__global__ __launch_bounds__(256) void prep_B(const float* __restrict__ Wrel,
                                              const float* __restrict__ Wroot,
                                              u16* __restrict__ Bt) {
    int i = blockIdx.x * 256 + threadIdx.x;
    if (i >= FD * KT) return;
    int k = i % KT;
    int o = i / KT;
    float v = (k < 512) ? Wrel[(size_t)k * FD + o] : Wroot[(size_t)(k - 512) * FD + o];
    Bt[i] = f2b(v);
}

// ---------- gemm_y: Y[r] = X @ Bt5[r]^T (r18-proven) ----------
__global__ __launch_bounds__(256) void gemm_y(const u16* __restrict__ X,
                                              const u16* __restrict__ Bt5,
                                              u16* __restrict__ Y) {
    __shared__ u16 As[2][8192];
    int blk = blockIdx.x;
    int rel = blk / NCHK;
    int chunk = blk - rel * NCHK;
    int row0 = chunk * 128;
    int tid = threadIdx.x;
    int wid = tid >> 6, lane = tid & 63;
    int wm = wid >> 1, wn = wid & 1;
    int lr = lane & 15, hi = lane >> 4;
    const u16* Btr = Bt5 + (size_t)rel * FD * FD;
    u16* C = Y + (size_t)rel * NN * FD;

    int srow = wid * 8 + (lane >> 3);
    int sg = (lane & 7) ^ ((lane >> 3) & 7);
#pragma unroll
    for (int s = 0; s < 2; ++s)
#pragma unroll
        for (int i = 0; i < 4; ++i) {
            int r = i * 32 + srow;
            int gr = row0 + r;
            gload_lds16(X + (size_t)gr * FD + s * 64 + sg * 8,
                        (char*)As[s] + i * 4096 + wid * 1024);
        }
    __syncthreads();

    f32x4 acc[4][4];
#pragma unroll
    for (int i = 0; i < 4; ++i)
#pragma unroll
        for (int j = 0; j < 4; ++j) acc[i][j] = (f32x4){0.f, 0.f, 0.f, 0.f};

#pragma unroll
    for (int t = 0; t < 2; ++t) {
#pragma unroll
        for (int kk = 0; kk < 2; ++kk) {
            bf16x8 bfr[4], afr[4];
#pragma unroll
            for (int ni = 0; ni < 4; ++ni) {
                int col = wn * 64 + ni * 16 + lr;
                bfr[ni] = *reinterpret_cast<const bf16x8*>(
                    Btr + (size_t)col * FD + t * 64 + kk * 32 + hi * 8);
            }
#pragma unroll
            for (int mi = 0; mi < 4; ++mi) {
                int r = wm * 64 + mi * 16 + lr;
                int sp = (kk * 4 + hi) ^ (r & 7);
                afr[mi] = *reinterpret_cast<const bf16x8*>((char*)As[t] + r * 128 + sp * 16);
            }
#pragma unroll
            for (int mi = 0; mi < 4; ++mi)
#pragma unroll
                for (int ni = 0; ni < 4; ++ni)
                    acc[mi][ni] = __builtin_amdgcn_mfma_f32_16x16x32_bf16(afr[mi], bfr[ni], acc[mi][ni], 0, 0, 0);
        }
    }
#pragma unroll
    for (int mi = 0; mi < 4; ++mi)
#pragma unroll
        for (int ni = 0; ni < 4; ++ni) {
            int col = wn * 64 + ni * 16 + lr;
#pragma unroll
            for (int rg = 0; rg < 4; ++rg) {
                int row = row0 + wm * 64 + mi * 16 + hi * 4 + rg;
                if (row < NN) C[(size_t)row * FD + col] = f2b(acc[mi][ni][rg]);
            }
        }
}

// ---------- layer-1 aggregation over the |S| compact rows ----------
__global__ __launch_bounds__(256) void agg_s(const int* __restrict__ cnts,
                                             const int* __restrict__ offs6s,
                                             const int* __restrict__ spack1,
                                             const int* __restrict__ snode,
                                             const u32* __restrict__ Y,   // u32 view, row 5*NN = 0
                                             const float* __restrict__ bias,
                                             u16* __restrict__ h1s) {
    int wid = threadIdx.x >> 6, lane = threadIdx.x & 63;
    int row = blockIdx.x * 4 + wid;
    if (row >= cnts[0]) return;

    const int* ob = offs6s + (size_t)row * 6;
    int o0 = __builtin_amdgcn_readfirstlane(ob[0]);
    int o1 = __builtin_amdgcn_readfirstlane(ob[1]);
    int o2 = __builtin_amdgcn_readfirstlane(ob[2]);
    int o3 = __builtin_amdgcn_readfirstlane(ob[3]);
    int o4 = __builtin_amdgcn_readfirstlane(ob[4]);
    int oL = __builtin_amdgcn_readfirstlane(ob[5]);

    float a00 = 0, a01 = 0, a10 = 0, a11 = 0, a20 = 0, a21 = 0, a30 = 0, a31 = 0;

    for (int e = o0; e < oL; e += 8) {
        int p[8];
        u32 v[8];
#pragma unroll
        for (int j = 0; j < 8; ++j)
            p[j] = __builtin_amdgcn_readfirstlane(spack1[e + j]);
#pragma unroll
        for (int j = 0; j < 8; ++j) v[j] = Y[(size_t)p[j] * 64 + lane];
#pragma unroll
        for (int j = 0; j < 8; ++j) {
            int ij = e + j;
            float f0 = b2f_lo(v[j]);
            float f1 = b2f_hi(v[j]);
            if (ij < o1)      { a00 += f0; a01 += f1; }
            else if (ij < o2) { a10 += f0; a11 += f1; }
            else if (ij < o3) { a20 += f0; a21 += f1; }
            else              { a30 += f0; a31 += f1; }   // pads read zero row
        }
    }

    int d0 = o1 - o0, d1 = o2 - o1, d2 = o3 - o2, d3 = o4 - o3;
    float s0 = 1.0f / (float)(d0 > 1 ? d0 : 1);
    float s1 = 1.0f / (float)(d1 > 1 ? d1 : 1);
    float s2 = 1.0f / (float)(d2 > 1 ? d2 : 1);
    float s3 = 1.0f / (float)(d3 > 1 ? d3 : 1);
    float sum0 = a00 * s0 + a10 * s1 + a20 * s2 + a30 * s3;
    float sum1 = a01 * s0 + a11 * s1 + a21 * s2 + a31 * s3;
    int node = __builtin_amdgcn_readfirstlane(snode[row]);
    u32 rv = Y[((size_t)4 * NN + node) * 64 + lane];
    float2 bb = *reinterpret_cast<const float2*>(bias + lane * 2);
    float r0 = fmaxf(sum0 + b2f_lo(rv) + bb.x, 0.f);
    float r1 = fmaxf(sum1 + b2f_hi(rv) + bb.y, 0.f);
    *(u32*)(h1s + (size_t)row * FD + lane * 2) = pack2(r0, r1);
}

// ---------- layer-2 aggregation (2048 query rows) from compact h1s ----------
__global__ __launch_bounds__(256) void agg_q2(const int* __restrict__ offs2,
                                              const int* __restrict__ spack2,
                                              const u32* __restrict__ h1s4,   // row MAXS = 0
                                              const int* __restrict__ nest,
                                              const int* __restrict__ food,
                                              const int* __restrict__ tidm,
                                              const int* __restrict__ sid,
                                              u16* __restrict__ Aout,
                                              int* __restrict__ sidq) {
    int wid = threadIdx.x >> 6, lane = threadIdx.x & 63;
    int row = blockIdx.x * 4 + wid;
    if (row >= 2 * NQ) return;
    int q = (row < NQ) ? nest[row] : food[row - NQ];
    q = __builtin_amdgcn_readfirstlane(q);
    int tq = __builtin_amdgcn_readfirstlane(tidm[q]);
    if (lane == 0) sidq[row] = sid[q];
    const int* ob = offs2 + (size_t)tq * 4;
    int o[5];
#pragma unroll
    for (int i = 0; i < 5; ++i) o[i] = __builtin_amdgcn_readfirstlane(ob[i]);
    u16* Ao = Aout + (size_t)row * KA + lane * 2;
#pragma unroll
    for (int r = 0; r < 4; ++r) {
        int s = o[r], t = o[r + 1], last = t - 1;
        float a0 = 0, a1 = 0;
        for (int e = s; e < t; e += 8) {
            int p[8];
            u32 v[8];
#pragma unroll
            for (int j = 0; j < 8; ++j) {
                int ij = e + j;
                int cl = ij <= last ? ij : last;
                int pv = __builtin_amdgcn_readfirstlane(spack2[cl]);
                p[j] = (ij <= last) ? pv : MAXS;   // dummy zero row
            }
#pragma unroll
            for (int j = 0; j < 8; ++j) v[j] = h1s4[(size_t)p[j] * 64 + lane];
#pragma unroll
            for (int j = 0; j < 8; ++j) { a0 += b2f_lo(v[j]); a1 += b2f_hi(v[j]); }
        }
        int d = t - s;
        float sc = 1.0f / (float)(d > 1 ? d : 1);
        *(u32*)(Ao + r * 128) = pack2(a0 * sc, a1 * sc);
    }
}

// ---------- layer-2 GEMM (2048 rows): r17 3-buffer counted-vmcnt pipeline ----------
__global__ __launch_bounds__(256) void gemm_lds3(const u16* __restrict__ A,
                                                 const u16* __restrict__ rootSrc,
                                                 const int* __restrict__ rootIdx,
                                                 const u16* __restrict__ Bt,
                                                 const float* __restrict__ bias,
                                                 float* __restrict__ Cout, int M) {
    __shared__ u16 As[3][8192];
    int tid = threadIdx.x;
    int wid = tid >> 6, lane = tid & 63;
    int wm = wid >> 1, wn = wid & 1;
    int lr = lane & 15, hi = lane >> 4;
    int row0 = blockIdx.x * 128;

    f32x4 acc[4][4];
#pragma unroll
    for (int i = 0; i < 4; ++i)
#pragma unroll
        for (int j = 0; j < 4; ++j) acc[i][j] = (f32x4){0.f, 0.f, 0.f, 0.f};

    int srow = wid * 8 + (lane >> 3);
    int sg = (lane & 7) ^ ((lane >> 3) & 7);

    auto stage = [&](int t, int buf) {
#pragma unroll
        for (int i = 0; i < 4; ++i) {
            int r = i * 32 + srow;
            int gr = row0 + r;
            const u16* src;
            if (t < 8) {
                src = A + (size_t)gr * KA + t * 64 + sg * 8;
            } else {
                int idx = rootIdx[gr];
                src = rootSrc + (size_t)idx * FD + (t - 8) * 64 + sg * 8;
            }
            gload_lds16(src, (char*)As[buf] + i * 4096 + wid * 1024);
        }
    };

    stage(0, 0);
    stage(1, 1);

    for (int t = 0; t < 10; ++t) {
        int cur = t % 3;
        bf16x8 bfr[2][4];
#pragma unroll
        for (int kk = 0; kk < 2; ++kk)
#pragma unroll
            for (int ni = 0; ni < 4; ++ni) {
                int col = wn * 64 + ni * 16 + lr;
                bfr[kk][ni] = *reinterpret_cast<const bf16x8*>(
                    Bt + (size_t)col * KT + t * 64 + kk * 32 + hi * 8);
            }
        bool staged = (t + 2 < 10);
        if (staged) stage(t + 2, (t + 2) % 3);
        if (staged) asm volatile("s_waitcnt vmcnt(4)" ::: "memory");
        else        asm volatile("s_waitcnt vmcnt(0)" ::: "memory");
        __builtin_amdgcn_s_barrier();
        __builtin_amdgcn_sched_barrier(0);
#pragma unroll
        for (int kk = 0; kk < 2; ++kk) {
            bf16x8 afr[4];
#pragma unroll
            for (int mi = 0; mi < 4; ++mi) {
                int r = wm * 64 + mi * 16 + lr;
                int sp = (kk * 4 + hi) ^ (r & 7);
                afr[mi] = *reinterpret_cast<const bf16x8*>((char*)As[cur] + r * 128 + sp * 16);
            }
#pragma unroll
            for (int mi = 0; mi < 4; ++mi)
#pragma unroll
                for (int ni = 0; ni < 4; ++ni)
                    acc[mi][ni] = __builtin_amdgcn_mfma_f32_16x16x32_bf16(afr[mi], bfr[kk][ni], acc[mi][ni], 0, 0, 0);
        }
        asm volatile("s_waitcnt lgkmcnt(0)" ::: "memory");
        __builtin_amdgcn_s_barrier();
    }

#pragma unroll
    for (int mi = 0; mi < 4; ++mi)
#pragma unroll
        for (int ni = 0; ni < 4; ++ni) {
            int col = wn * 64 + ni * 16 + lr;
            float bv = bias[col];
#pragma unroll
            for (int rg = 0; rg < 4; ++rg) {
                int row = row0 + wm * 64 + mi * 16 + hi * 4 + rg;
                if (row < M) Cout[(size_t)row * FD + col] = acc[mi][ni][rg] + bv;
            }
        }
}

// ---------- final FC ----------
__global__ __launch_bounds__(256) void fc_kernel(const float* __restrict__ h2q,
                                                 const float* __restrict__ Wfc,
                                                 const float* __restrict__ bfc,
                                                 float* __restrict__ out) {
    __shared__ float comb[2 * FD];
    int q = blockIdx.x, t = threadIdx.x;
    if (t < FD) comb[t] = h2q[(size_t)q * FD + t];
    else comb[t] = h2q[(size_t)(NQ + q) * FD + (t - FD)];
    __syncthreads();
    float s = bfc[t];
#pragma unroll 4
    for (int k = 0; k < 2 * FD; ++k) s += comb[k] * Wfc[(size_t)k * HIDN + t];
    out[(size_t)q * HIDN + t] = fmaxf(s, 0.f);
}

extern "C" void kernel_launch(void* const* d_in, const int* in_sizes, int n_in,
                              void* d_out, int out_size, void* d_ws, size_t ws_size,
                              hipStream_t stream) {
    const float* x      = (const float*)d_in[0];
    const int*   ei     = (const int*)d_in[1];
    const int*   et     = (const int*)d_in[2];
    const int*   nest   = (const int*)d_in[3];
    const int*   food   = (const int*)d_in[4];
    const float* Wrel1  = (const float*)d_in[5];
    const float* Wroot1 = (const float*)d_in[6];
    const float* b1     = (const float*)d_in[7];
    const float* Wrel2  = (const float*)d_in[8];
    const float* Wroot2 = (const float*)d_in[9];
    const float* b2     = (const float*)d_in[10];
    const float* Wfc    = (const float*)d_in[11];
    const float* bfc    = (const float*)d_in[12];
    float* out = (float*)d_out;

    char* w = (char*)d_ws;
    size_t off = 0;
    auto take = [&](size_t b) {
        char* p = w + off;
        off += b;
        off = (off + 255) & ~(size_t)255;
        return p;
    };
    // --- zeroed-every-call region (one memset) ---
    size_t zero0 = off;
    int* cnts   = (int*)take(256);                       // [0]=Scnt [1]=Tcnt [2]=l2cnt
    u8* bmT     = (u8*)take(NN);
    u8* bmS     = (u8*)take(NN);
    int* deg2   = (int*)take(8192 * 4);
    int* deg1   = (int*)take((size_t)4 * MAXS * 4);
    size_t zeroSz = off - zero0;
    char* zbase = w + zero0;
    // --- rest ---
    int* oS     = (int*)take((size_t)NCHB * 4);
    int* oT     = (int*)take((size_t)NCHB * 4);
    int* c1     = (int*)take((size_t)NCH1 * 4);
    int* o1     = (int*)take((size_t)NCH1 * 4);
    int* sid    = (int*)take((size_t)NN * 4);
    int* tidm   = (int*)take((size_t)NN * 4);
    int* snode  = (int*)take((size_t)MAXS * 4);
    u32* l2a    = (u32*)take((size_t)MAXL2 * 4);
    u32* l2d    = (u32*)take((size_t)MAXL2 * 4);
    int* offs2  = (int*)take((size_t)8193 * 4);
    int* cur2   = (int*)take((size_t)8192 * 4);
    int* spack2 = (int*)take((size_t)MAXL2 * 4);
    int* offs6s = (int*)take((size_t)MAXS * 6 * 4);
    int* cur1   = (int*)take((size_t)4 * MAXS * 4);
    int* spack1 = (int*)take(((size_t)NE + 8 * MAXS) * 4);
    int* sidq   = (int*)take((size_t)2 * NQ * 4);
    u16* xh     = (u16*)take((size_t)MPAD * FD * 2);
    u16* Bt5    = (u16*)take((size_t)5 * FD * FD * 2);
    u16* Bt2    = (u16*)take((size_t)FD * KT * 2);
    u16* Y      = (u16*)take(((size_t)5 * NN + 1) * FD * 2);   // row 5*NN = zeros
    u16* h1s    = (u16*)take(((size_t)MAXS + 1) * FD * 2);     // row MAXS = zeros
    u16* A2     = (u16*)take((size_t)2 * NQ * KA * 2);
    float* h2q  = (float*)take((size_t)2 * NQ * FD * 4);

    hipMemsetAsync(zbase, 0, zeroSz, stream);
    hipMemsetAsync(Y + (size_t)5 * NN * FD, 0, FD * 2, stream);
    hipMemsetAsync(h1s + (size_t)MAXS * FD, 0, FD * 2, stream);

    cvt_bf16<<<((NN * FD / 4) + 255) / 256, 256, 0, stream>>>(x, xh, NN * FD);
    prep_B5<<<(5 * FD * FD + 255) / 256, 256, 0, stream>>>(Wrel1, Wroot1, Bt5);
    prep_B<<<(FD * KT + 255) / 256, 256, 0, stream>>>(Wrel2, Wroot2, Bt2);

    mark_T<<<(2 * NQ + 255) / 256, 256, 0, stream>>>(nest, food, bmT, bmS);
    filter_l2<<<NBE, 256, 0, stream>>>(ei, et, bmT, bmS, cnts, l2a, l2d);
    bm_chunk<<<NCHB, 256, 0, stream>>>(bmS, bmT, oS, oT);   // reuse oS/oT as chunk sums then offsets
    bm_scan<<<1, 512, 0, stream>>>(oS, oT, oS, oT, cnts);   // in-place: reads then writes same slots
    bm_write<<<NCHB, 256, 0, stream>>>(bmS, bmT, oS, oT, sid, tidm, snode);

    l2_count<<<128, 256, 0, stream>>>(cnts, l2a, l2d, tidm, deg2);
    l2_scan<<<1, 1024, 0, stream>>>(deg2, offs2, cur2);
    l2_scatter<<<128, 256, 0, stream>>>(cnts, l2a, l2d, tidm, sid, cur2, spack2);

    l1_count<<<NBE, 256, 0, stream>>>(ei, et, bmS, sid, deg1);
    l1_chunk<<<NCH1, 256, 0, stream>>>(deg1, c1);
    l1_scan<<<1, 256, 0, stream>>>(c1, o1);
    l1_write<<<NCH1, 256, 0, stream>>>(deg1, o1, offs6s, cur1, spack1);
    l1_scatter<<<NBE, 256, 0, stream>>>(ei, et, bmS, sid, cur1, spack1);

    gemm_y<<<5 * NCHK, 256, 0, stream>>>(xh, Bt5, Y);

    agg_s<<<MAXS / 4, 256, 0, stream>>>(cnts, offs6s, spack1, snode, (const u32*)Y, b1, h1s);

    agg_q2<<<(2 * NQ + 3) / 4, 256, 0, stream>>>(offs2, spack2, (const u32*)h1s,
                                                 nest, food, tidm, sid, A2, sidq);
    gemm_lds3<<<(2 * NQ) / 128, 256, 0, stream>>>(A2, h1s, sidq, Bt2, b2, h2q, 2 * NQ);
    fc_kernel<<<NQ, 256, 0, stream>>>(h2q, Wfc, bfc, out);
}

// Round 20
// 229.231 us; speedup vs baseline: 1.1313x; 1.1313x over previous
//
#include <hip/hip_runtime.h>
#include <stdint.h>

#define NN 100000
#define NE 1600000
#define NR 4
#define FD 128
#define KA 512            // A matrix cols (rel blocks only; root handled separately)
#define KT 640
#define NQ 1024
#define HIDN 256

#define MPAD 100096                    // NN rounded up to 128
#define NBE ((NE + 2047) / 2048)       // 782 edge-scan blocks
#define NCHB ((NN + 255) / 256)        // 391 bitmap chunks
#define MAXS 49152                     // upper bound on |S| (expected ~30k)
#define NCH1 (MAXS / 256)              // 192
#define MAXL2 65536                    // upper bound on layer-2 edges (expected ~33k)

using u16 = unsigned short;
using u32 = unsigned int;
using u8 = unsigned char;
typedef __attribute__((ext_vector_type(8))) __bf16 bf16x8;
typedef __attribute__((ext_vector_type(4))) float f32x4;

__device__ __forceinline__ u16 f2b(float f) {
    u32 u = __builtin_bit_cast(u32, f);
    u32 r = u + 0x7FFFu + ((u >> 16) & 1u);   // round-to-nearest-even
    return (u16)(r >> 16);
}
__device__ __forceinline__ float b2f_lo(u32 v) { return __builtin_bit_cast(float, v << 16); }
__device__ __forceinline__ float b2f_hi(u32 v) { return __builtin_bit_cast(float, v & 0xFFFF0000u); }
__device__ __forceinline__ u32 pack2(float a, float b) {
    return (u32)f2b(a) | ((u32)f2b(b) << 16);
}
__device__ __forceinline__ void gload_lds16(const void* g, void* l) {
    __builtin_amdgcn_global_load_lds((const __attribute__((address_space(1))) u32*)g,
                                     (__attribute__((address_space(3))) u32*)l, 16, 0, 0);
}

// ---------- mark query nodes ----------
__global__ __launch_bounds__(256) void mark_T(const int* __restrict__ nest,
                                              const int* __restrict__ food,
                                              u8* __restrict__ bmT, u8* __restrict__ bmS) {
    int i = blockIdx.x * 256 + threadIdx.x;
    if (i < NQ)          { int q = nest[i];      bmT[q] = 1; bmS[q] = 1; }
    else if (i < 2 * NQ) { int q = food[i - NQ]; bmT[q] = 1; bmS[q] = 1; }
}

// ---------- filter layer-2 edges (dst in T); mark their sources in S ----------
__global__ __launch_bounds__(256) void filter_l2(const int* __restrict__ ei,
                                                 const int* __restrict__ et,
                                                 const u8* __restrict__ bmT,
                                                 u8* __restrict__ bmS,
                                                 int* __restrict__ cnts,
                                                 u32* __restrict__ l2a,
                                                 u32* __restrict__ l2d) {
    __shared__ int lcnt, lbase;
    __shared__ u32 ba[2048], bd[2048];
    int t = threadIdx.x;
    if (t == 0) lcnt = 0;
    __syncthreads();
    int e0 = blockIdx.x * 2048;
    for (int j = 0; j < 8; ++j) {
        int e = e0 + j * 256 + t;
        if (e < NE) {
            int dst = ei[NE + e];
            if (bmT[dst]) {
                int src = ei[e];
                int r = et[e];
                int pos = atomicAdd(&lcnt, 1);
                ba[pos] = (u32)src | ((u32)r << 17);
                bd[pos] = (u32)dst;
                bmS[src] = 1;
            }
        }
    }
    __syncthreads();
    if (t == 0) lbase = atomicAdd(&cnts[2], lcnt);
    __syncthreads();
    for (int i = t; i < lcnt; i += 256) {
        l2a[lbase + i] = ba[i];
        l2d[lbase + i] = bd[i];
    }
}

// ---------- compact S/T ids ----------
__global__ __launch_bounds__(256) void bm_chunk(const u8* __restrict__ bmS,
                                                const u8* __restrict__ bmT,
                                                int* __restrict__ cS, int* __restrict__ cT) {
    __shared__ int sS[256], sT[256];
    int b = blockIdx.x, t = threadIdx.x;
    int n = b * 256 + t;
    int vs = (n < NN) ? bmS[n] : 0;
    int vt = (n < NN) ? bmT[n] : 0;
    sS[t] = vs; sT[t] = vt;
    __syncthreads();
    for (int o = 128; o > 0; o >>= 1) {
        if (t < o) { sS[t] += sS[t + o]; sT[t] += sT[t + o]; }
        __syncthreads();
    }
    if (t == 0) { cS[b] = sS[0]; cT[b] = sT[0]; }
}

__global__ __launch_bounds__(512) void bm_scan(const int* __restrict__ cS,
                                               const int* __restrict__ cT,
                                               int* __restrict__ oS, int* __restrict__ oT,
                                               int* __restrict__ cnts) {
    __shared__ int sS[512], sT[512];
    int t = threadIdx.x;
    int vs = (t < NCHB) ? cS[t] : 0;
    int vt = (t < NCHB) ? cT[t] : 0;
    sS[t] = vs; sT[t] = vt;
    __syncthreads();
    for (int o = 1; o < 512; o <<= 1) {
        int a = (t >= o) ? sS[t - o] : 0;
        int c = (t >= o) ? sT[t - o] : 0;
        __syncthreads();
        sS[t] += a; sT[t] += c;
        __syncthreads();
    }
    if (t < NCHB) { oS[t] = sS[t] - vs; oT[t] = sT[t] - vt; }
    if (t == NCHB - 1) { cnts[0] = sS[t]; cnts[1] = sT[t]; }
}

__global__ __launch_bounds__(256) void bm_write(const u8* __restrict__ bmS,
                                                const u8* __restrict__ bmT,
                                                const int* __restrict__ oS,
                                                const int* __restrict__ oT,
                                                int* __restrict__ sid, int* __restrict__ tidm,
                                                int* __restrict__ snode) {
    __shared__ int sS[256], sT[256];
    int b = blockIdx.x, t = threadIdx.x;
    int n = b * 256 + t;
    int vs = (n < NN) ? bmS[n] : 0;
    int vt = (n < NN) ? bmT[n] : 0;
    sS[t] = vs; sT[t] = vt;
    __syncthreads();
    for (int o = 1; o < 256; o <<= 1) {
        int a = (t >= o) ? sS[t - o] : 0;
        int c = (t >= o) ? sT[t - o] : 0;
        __syncthreads();
        sS[t] += a; sT[t] += c;
        __syncthreads();
    }
    if (n < NN) {
        int is = oS[b] + sS[t] - vs;
        int it = oT[b] + sT[t] - vt;
        sid[n] = is;
        tidm[n] = it;
        if (vs) snode[is] = n;
    }
}

// ---------- layer-2 CSR over (tid, rel) keys ----------
__global__ __launch_bounds__(256) void l2_count(const int* __restrict__ cnts,
                                                const u32* __restrict__ l2a,
                                                const u32* __restrict__ l2d,
                                                const int* __restrict__ tidm,
                                                int* __restrict__ deg2) {
    int n = cnts[2];
    for (int i = blockIdx.x * 256 + threadIdx.x; i < n; i += gridDim.x * 256)
        atomicAdd(&deg2[tidm[l2d[i]] * 4 + ((l2a[i] >> 17) & 3)], 1);
}

__global__ __launch_bounds__(1024) void l2_scan(const int* __restrict__ deg2,
                                                int* __restrict__ offs2,
                                                int* __restrict__ cur2) {
    __shared__ int sm[1024];
    int t = threadIdx.x;
    int v[8];
    int s = 0;
    for (int j = 0; j < 8; ++j) { v[j] = deg2[t * 8 + j]; s += v[j]; }
    sm[t] = s;
    __syncthreads();
    for (int o = 1; o < 1024; o <<= 1) {
        int n = (t >= o) ? sm[t - o] : 0;
        __syncthreads();
        sm[t] += n;
        __syncthreads();
    }
    int ex = sm[t] - s;
    for (int j = 0; j < 8; ++j) { offs2[t * 8 + j] = ex; cur2[t * 8 + j] = ex; ex += v[j]; }
    if (t == 1023) offs2[8192] = ex;
}

__global__ __launch_bounds__(256) void l2_scatter(const int* __restrict__ cnts,
                                                  const u32* __restrict__ l2a,
                                                  const u32* __restrict__ l2d,
                                                  const int* __restrict__ tidm,
                                                  const int* __restrict__ sid,
                                                  int* __restrict__ cur2,
                                                  int* __restrict__ spack2) {
    int n = cnts[2];
    for (int i = blockIdx.x * 256 + threadIdx.x; i < n; i += gridDim.x * 256) {
        u32 a = l2a[i];
        int k = tidm[l2d[i]] * 4 + ((a >> 17) & 3);
        int pos = atomicAdd(&cur2[k], 1);
        spack2[pos] = sid[a & 0x1FFFFu];
    }
}

// ---------- layer-1 CSR over (sid, rel) keys, padded to x8 ----------
__global__ __launch_bounds__(256) void l1_count(const int* __restrict__ ei,
                                                const int* __restrict__ et,
                                                const u8* __restrict__ bmS,
                                                const int* __restrict__ sid,
                                                int* __restrict__ deg1) {
    int e0 = blockIdx.x * 2048;
    int t = threadIdx.x;
    for (int j = 0; j < 8; ++j) {
        int e = e0 + j * 256 + t;
        if (e < NE) {
            int dst = ei[NE + e];
            if (bmS[dst]) atomicAdd(&deg1[sid[dst] * 4 + et[e]], 1);
        }
    }
}

__global__ __launch_bounds__(256) void l1_chunk(const int* __restrict__ deg1,
                                                int* __restrict__ c1) {
    __shared__ int sm[256];
    int b = blockIdx.x, t = threadIdx.x;
    int n = b * 256 + t;
    int s = deg1[4 * n] + deg1[4 * n + 1] + deg1[4 * n + 2] + deg1[4 * n + 3];
    sm[t] = (s + 7) & ~7;
    __syncthreads();
    for (int o = 128; o > 0; o >>= 1) {
        if (t < o) sm[t] += sm[t + o];
        __syncthreads();
    }
    if (t == 0) c1[b] = sm[0];
}

__global__ __launch_bounds__(256) void l1_scan(const int* __restrict__ c1,
                                               int* __restrict__ o1) {
    __shared__ int sm[256];
    int t = threadIdx.x;
    int v = (t < NCH1) ? c1[t] : 0;
    sm[t] = v;
    __syncthreads();
    for (int o = 1; o < 256; o <<= 1) {
        int n = (t >= o) ? sm[t - o] : 0;
        __syncthreads();
        sm[t] += n;
        __syncthreads();
    }
    if (t < NCH1) o1[t] = sm[t] - v;
}

__global__ __launch_bounds__(256) void l1_write(const int* __restrict__ deg1,
                                                const int* __restrict__ o1,
                                                int* __restrict__ offs6s,
                                                int* __restrict__ cur1,
                                                int* __restrict__ spack1) {
    __shared__ int sm[256];
    int b = blockIdx.x, t = threadIdx.x;
    int n = b * 256 + t;
    int d0 = deg1[4 * n], d1 = deg1[4 * n + 1], d2 = deg1[4 * n + 2], d3 = deg1[4 * n + 3];
    int s = d0 + d1 + d2 + d3;
    int sp = (s + 7) & ~7;
    sm[t] = sp;
    __syncthreads();
    for (int o = 1; o < 256; o <<= 1) {
        int v = (t >= o) ? sm[t - o] : 0;
        __syncthreads();
        sm[t] += v;
        __syncthreads();
    }
    int e0 = o1[b] + sm[t] - sp;
    int e1 = e0 + d0, e2 = e1 + d1, e3 = e2 + d2, e4 = e3 + d3, eL = e0 + sp;
    int* o6 = offs6s + (size_t)n * 6;
    o6[0] = e0; o6[1] = e1; o6[2] = e2; o6[3] = e3; o6[4] = e4; o6[5] = eL;
    cur1[4 * n] = e0; cur1[4 * n + 1] = e1; cur1[4 * n + 2] = e2; cur1[4 * n + 3] = e3;
    for (int i = e4; i < eL; ++i) spack1[i] = NN;   // pads -> xh zero row
}

__global__ __launch_bounds__(256) void l1_scatter(const int* __restrict__ ei,
                                                  const int* __restrict__ et,
                                                  const u8* __restrict__ bmS,
                                                  const int* __restrict__ sid,
                                                  int* __restrict__ cur1,
                                                  int* __restrict__ spack1) {
    int e0 = blockIdx.x * 2048;
    int t = threadIdx.x;
    for (int j = 0; j < 8; ++j) {
        int e = e0 + j * 256 + t;
        if (e < NE) {
            int dst = ei[NE + e];
            if (bmS[dst]) {
                int pos = atomicAdd(&cur1[sid[dst] * 4 + et[e]], 1);
                spack1[pos] = ei[e];
            }
        }
    }
}

// ---------- conversions / weight prep ----------
__global__ __launch_bounds__(256) void cvt_bf16(const float* __restrict__ in,
                                                u16* __restrict__ outp, int n) {
    int i = blockIdx.x * 256 + threadIdx.x;
    int idx = i * 4;
    if (idx >= n) return;
    float4 v = *(const float4*)(in + idx);
    u32 lo = (u32)f2b(v.x) | ((u32)f2b(v.y) << 16);
    u32 hi = (u32)f2b(v.z) | ((u32)f2b(v.w) << 16);
    *(uint2*)(outp + idx) = make_uint2(lo, hi);
}

__global__ __launch_bounds__(256) void prep_B(const float* __restrict__ Wrel,
                                              const float* __restrict__ Wroot,
                                              u16* __restrict__ Bt) {
    int i = blockIdx.x * 256 + threadIdx.x;
    if (i >= FD * KT) return;
    int k = i % KT;
    int o = i / KT;
    float v = (k < 512) ? Wrel[(size_t)k * FD + o] : Wroot[(size_t)(k - 512) * FD + o];
    Bt[i] = f2b(v);
}

// ---------- layer-1 aggregation over |S| compact rows, gather from xh ----------
__global__ __launch_bounds__(256) void agg_s(const int* __restrict__ cnts,
                                             const int* __restrict__ offs6s,
                                             const int* __restrict__ spack1,
                                             const u32* __restrict__ fp,   // xh u32 view, row NN = 0
                                             u16* __restrict__ Aout) {
    int wid = threadIdx.x >> 6, lane = threadIdx.x & 63;
    int row = blockIdx.x * 4 + wid;
    if (row >= cnts[0]) return;

    const int* ob = offs6s + (size_t)row * 6;
    int o0 = __builtin_amdgcn_readfirstlane(ob[0]);
    int o1 = __builtin_amdgcn_readfirstlane(ob[1]);
    int o2 = __builtin_amdgcn_readfirstlane(ob[2]);
    int o3 = __builtin_amdgcn_readfirstlane(ob[3]);
    int o4 = __builtin_amdgcn_readfirstlane(ob[4]);
    int oL = __builtin_amdgcn_readfirstlane(ob[5]);

    float a00 = 0, a01 = 0, a10 = 0, a11 = 0, a20 = 0, a21 = 0, a30 = 0, a31 = 0;

    for (int e = o0; e < oL; e += 8) {
        int p[8];
        u32 v[8];
#pragma unroll
        for (int j = 0; j < 8; ++j)
            p[j] = __builtin_amdgcn_readfirstlane(spack1[e + j]);
#pragma unroll
        for (int j = 0; j < 8; ++j) v[j] = fp[(size_t)p[j] * 64 + lane];
#pragma unroll
        for (int j = 0; j < 8; ++j) {
            int ij = e + j;
            float f0 = b2f_lo(v[j]);
            float f1 = b2f_hi(v[j]);
            if (ij < o1)      { a00 += f0; a01 += f1; }
            else if (ij < o2) { a10 += f0; a11 += f1; }
            else if (ij < o3) { a20 += f0; a21 += f1; }
            else              { a30 += f0; a31 += f1; }   // pads read zero row
        }
    }

    int d0 = o1 - o0, d1 = o2 - o1, d2 = o3 - o2, d3 = o4 - o3;
    float s0 = 1.0f / (float)(d0 > 1 ? d0 : 1);
    float s1 = 1.0f / (float)(d1 > 1 ? d1 : 1);
    float s2 = 1.0f / (float)(d2 > 1 ? d2 : 1);
    float s3 = 1.0f / (float)(d3 > 1 ? d3 : 1);
    u16* Ao = Aout + (size_t)row * KA + lane * 2;
    __builtin_nontemporal_store(pack2(a00 * s0, a01 * s0), (u32*)(Ao + 0));
    __builtin_nontemporal_store(pack2(a10 * s1, a11 * s1), (u32*)(Ao + 128));
    __builtin_nontemporal_store(pack2(a20 * s2, a21 * s2), (u32*)(Ao + 256));
    __builtin_nontemporal_store(pack2(a30 * s3, a31 * s3), (u32*)(Ao + 384));
}

// ---------- layer-2 aggregation (2048 query rows) from compact h1s ----------
__global__ __launch_bounds__(256) void agg_q2(const int* __restrict__ offs2,
                                              const int* __restrict__ spack2,
                                              const u32* __restrict__ h1s4,   // row MAXS = 0
                                              const int* __restrict__ nest,
                                              const int* __restrict__ food,
                                              const int* __restrict__ tidm,
                                              const int* __restrict__ sid,
                                              u16* __restrict__ Aout,
                                              int* __restrict__ sidq) {
    int wid = threadIdx.x >> 6, lane = threadIdx.x & 63;
    int row = blockIdx.x * 4 + wid;
    if (row >= 2 * NQ) return;
    int q = (row < NQ) ? nest[row] : food[row - NQ];
    q = __builtin_amdgcn_readfirstlane(q);
    int tq = __builtin_amdgcn_readfirstlane(tidm[q]);
    if (lane == 0) sidq[row] = sid[q];
    const int* ob = offs2 + (size_t)tq * 4;
    int o[5];
#pragma unroll
    for (int i = 0; i < 5; ++i) o[i] = __builtin_amdgcn_readfirstlane(ob[i]);
    u16* Ao = Aout + (size_t)row * KA + lane * 2;
#pragma unroll
    for (int r = 0; r < 4; ++r) {
        int s = o[r], t = o[r + 1], last = t - 1;
        float a0 = 0, a1 = 0;
        for (int e = s; e < t; e += 8) {
            int p[8];
            u32 v[8];
#pragma unroll
            for (int j = 0; j < 8; ++j) {
                int ij = e + j;
                int cl = ij <= last ? ij : last;
                int pv = __builtin_amdgcn_readfirstlane(spack2[cl]);
                p[j] = (ij <= last) ? pv : MAXS;   // dummy zero row
            }
#pragma unroll
            for (int j = 0; j < 8; ++j) v[j] = h1s4[(size_t)p[j] * 64 + lane];
#pragma unroll
            for (int j = 0; j < 8; ++j) { a0 += b2f_lo(v[j]); a1 += b2f_hi(v[j]); }
        }
        int d = t - s;
        float sc = 1.0f / (float)(d > 1 ? d : 1);
        *(u32*)(Ao + r * 128) = pack2(a0 * sc, a1 * sc);
    }
}

// ---------- GEMM: r17 3-buffer counted-vmcnt pipeline; M static or device ----------
__global__ __launch_bounds__(256) void gemm_lds3(const u16* __restrict__ A,
                                                 const u16* __restrict__ rootSrc,
                                                 const int* __restrict__ rootIdx,
                                                 const u16* __restrict__ Bt,
                                                 const float* __restrict__ bias,
                                                 void* __restrict__ Cout,
                                                 const int* __restrict__ Mptr, int Mstatic,
                                                 int relu, int outBf16) {
    int M = Mptr ? Mptr[0] : Mstatic;
    int row0 = blockIdx.x * 128;
    if (row0 >= M) return;
    __shared__ u16 As[3][8192];
    int tid = threadIdx.x;
    int wid = tid >> 6, lane = tid & 63;
    int wm = wid >> 1, wn = wid & 1;
    int lr = lane & 15, hi = lane >> 4;

    f32x4 acc[4][4];
#pragma unroll
    for (int i = 0; i < 4; ++i)
#pragma unroll
        for (int j = 0; j < 4; ++j) acc[i][j] = (f32x4){0.f, 0.f, 0.f, 0.f};

    int srow = wid * 8 + (lane >> 3);
    int sg = (lane & 7) ^ ((lane >> 3) & 7);

    auto stage = [&](int t, int buf) {
#pragma unroll
        for (int i = 0; i < 4; ++i) {
            int r = i * 32 + srow;
            int gr = row0 + r;
            const u16* src;
            if (t < 8) {
                src = A + (size_t)gr * KA + t * 64 + sg * 8;
            } else {
                int idx = rootIdx ? rootIdx[gr] : gr;
                if ((u32)idx > (u32)NN) idx = 0;   // clamp garbage beyond-M ids
                src = rootSrc + (size_t)idx * FD + (t - 8) * 64 + sg * 8;
            }
            gload_lds16(src, (char*)As[buf] + i * 4096 + wid * 1024);
        }
    };

    stage(0, 0);
    stage(1, 1);

    for (int t = 0; t < 10; ++t) {
        int cur = t % 3;
        bf16x8 bfr[2][4];
#pragma unroll
        for (int kk = 0; kk < 2; ++kk)
#pragma unroll
            for (int ni = 0; ni < 4; ++ni) {
                int col = wn * 64 + ni * 16 + lr;
                bfr[kk][ni] = *reinterpret_cast<const bf16x8*>(
                    Bt + (size_t)col * KT + t * 64 + kk * 32 + hi * 8);
            }
        bool staged = (t + 2 < 10);
        if (staged) stage(t + 2, (t + 2) % 3);
        if (staged) asm volatile("s_waitcnt vmcnt(4)" ::: "memory");
        else        asm volatile("s_waitcnt vmcnt(0)" ::: "memory");
        __builtin_amdgcn_s_barrier();
        __builtin_amdgcn_sched_barrier(0);
#pragma unroll
        for (int kk = 0; kk < 2; ++kk) {
            bf16x8 afr[4];
#pragma unroll
            for (int mi = 0; mi < 4; ++mi) {
                int r = wm * 64 + mi * 16 + lr;
                int sp = (kk * 4 + hi) ^ (r & 7);
                afr[mi] = *reinterpret_cast<const bf16x8*>((char*)As[cur] + r * 128 + sp * 16);
            }
#pragma unroll
            for (int mi = 0; mi < 4; ++mi)
#pragma unroll
                for (int ni = 0; ni < 4; ++ni)
                    acc[mi][ni] = __builtin_amdgcn_mfma_f32_16x16x32_bf16(afr[mi], bfr[kk][ni], acc[mi][ni], 0, 0, 0);
        }
        asm volatile("s_waitcnt lgkmcnt(0)" ::: "memory");
        __builtin_amdgcn_s_barrier();
    }

#pragma unroll
    for (int mi = 0; mi < 4; ++mi)
#pragma unroll
        for (int ni = 0; ni < 4; ++ni) {
            int col = wn * 64 + ni * 16 + lr;
            float bv = bias[col];
#pragma unroll
            for (int rg = 0; rg < 4; ++rg) {
                int row = row0 + wm * 64 + mi * 16 + hi * 4 + rg;
                if (row < M) {
                    float v = acc[mi][ni][rg] + bv;
                    if (relu) v = fmaxf(v, 0.f);
                    if (outBf16) ((u16*)Cout)[(size_t)row * FD + col] = f2b(v);
                    else ((float*)Cout)[(size_t)row * FD + col] = v;
                }
            }
        }
}

// ---------- final FC ----------
__global__ __launch_bounds__(256) void fc_kernel(const float* __restrict__ h2q,
                                                 const float* __restrict__ Wfc,
                                                 const float* __restrict__ bfc,
                                                 float* __restrict__ out) {
    __shared__ float comb[2 * FD];
    int q = blockIdx.x, t = threadIdx.x;
    if (t < FD) comb[t] = h2q[(size_t)q * FD + t];
    else comb[t] = h2q[(size_t)(NQ + q) * FD + (t - FD)];
    __syncthreads();
    float s = bfc[t];
#pragma unroll 4
    for (int k = 0; k < 2 * FD; ++k) s += comb[k] * Wfc[(size_t)k * HIDN + t];
    out[(size_t)q * HIDN + t] = fmaxf(s, 0.f);
}

extern "C" void kernel_launch(void* const* d_in, const int* in_sizes, int n_in,
                              void* d_out, int out_size, void* d_ws, size_t ws_size,
                              hipStream_t stream) {
    const float* x      = (const float*)d_in[0];
    const int*   ei     = (const int*)d_in[1];
    const int*   et     = (const int*)d_in[2];
    const int*   nest   = (const int*)d_in[3];
    const int*   food   = (const int*)d_in[4];
    const float* Wrel1  = (const float*)d_in[5];
    const float* Wroot1 = (const float*)d_in[6];
    const float* b1     = (const float*)d_in[7];
    const float* Wrel2  = (const float*)d_in[8];
    const float* Wroot2 = (const float*)d_in[9];
    const float* b2     = (const float*)d_in[10];
    const float* Wfc    = (const float*)d_in[11];
    const float* bfc    = (const float*)d_in[12];
    float* out = (float*)d_out;

    char* w = (char*)d_ws;
    size_t off = 0;
    auto take = [&](size_t b) {
        char* p = w + off;
        off += b;
        off = (off + 255) & ~(size_t)255;
        return p;
    };
    // --- zeroed-every-call region (one memset) ---
    size_t zero0 = off;
    int* cnts   = (int*)take(256);                       // [0]=Scnt [1]=Tcnt [2]=l2cnt
    u8* bmT     = (u8*)take(NN);
    u8* bmS     = (u8*)take(NN);
    int* deg2   = (int*)take(8192 * 4);
    int* deg1   = (int*)take((size_t)4 * MAXS * 4);
    int* snode  = (int*)take((size_t)MAXS * 4);          // zeroed: beyond-S root ids -> 0
    size_t zeroSz = off - zero0;
    char* zbase = w + zero0;
    // --- rest ---
    int* oS     = (int*)take((size_t)NCHB * 4);
    int* oT     = (int*)take((size_t)NCHB * 4);
    int* c1     = (int*)take((size_t)NCH1 * 4);
    int* o1     = (int*)take((size_t)NCH1 * 4);
    int* sid    = (int*)take((size_t)NN * 4);
    int* tidm   = (int*)take((size_t)NN * 4);
    u32* l2a    = (u32*)take((size_t)MAXL2 * 4);
    u32* l2d    = (u32*)take((size_t)MAXL2 * 4);
    int* offs2  = (int*)take((size_t)8193 * 4);
    int* cur2   = (int*)take((size_t)8192 * 4);
    int* spack2 = (int*)take((size_t)MAXL2 * 4);
    int* offs6s = (int*)take((size_t)MAXS * 6 * 4);
    int* cur1   = (int*)take((size_t)4 * MAXS * 4);
    int* spack1 = (int*)take(((size_t)NE + 8 * MAXS) * 4);
    int* sidq   = (int*)take((size_t)2 * NQ * 4);
    u16* xh     = (u16*)take((size_t)MPAD * FD * 2);           // row NN = zeros
    u16* Bt1    = (u16*)take((size_t)FD * KT * 2);
    u16* Bt2    = (u16*)take((size_t)FD * KT * 2);
    u16* A1s    = (u16*)take((size_t)MAXS * KA * 2);
    u16* h1s    = (u16*)take(((size_t)MAXS + 1) * FD * 2);     // row MAXS = zeros
    u16* A2     = (u16*)take((size_t)2 * NQ * KA * 2);
    float* h2q  = (float*)take((size_t)2 * NQ * FD * 4);

    hipMemsetAsync(zbase, 0, zeroSz, stream);
    hipMemsetAsync(xh + (size_t)NN * FD, 0, FD * 2, stream);
    hipMemsetAsync(h1s + (size_t)MAXS * FD, 0, FD * 2, stream);

    cvt_bf16<<<((NN * FD / 4) + 255) / 256, 256, 0, stream>>>(x, xh, NN * FD);
    prep_B<<<(FD * KT + 255) / 256, 256, 0, stream>>>(Wrel1, Wroot1, Bt1);
    prep_B<<<(FD * KT + 255) / 256, 256, 0, stream>>>(Wrel2, Wroot2, Bt2);

    mark_T<<<(2 * NQ + 255) / 256, 256, 0, stream>>>(nest, food, bmT, bmS);
    filter_l2<<<NBE, 256, 0, stream>>>(ei, et, bmT, bmS, cnts, l2a, l2d);
    bm_chunk<<<NCHB, 256, 0, stream>>>(bmS, bmT, oS, oT);
    bm_scan<<<1, 512, 0, stream>>>(oS, oT, oS, oT, cnts);
    bm_write<<<NCHB, 256, 0, stream>>>(bmS, bmT, oS, oT, sid, tidm, snode);

    l2_count<<<128, 256, 0, stream>>>(cnts, l2a, l2d, tidm, deg2);
    l2_scan<<<1, 1024, 0, stream>>>(deg2, offs2, cur2);
    l2_scatter<<<128, 256, 0, stream>>>(cnts, l2a, l2d, tidm, sid, cur2, spack2);

    l1_count<<<NBE, 256, 0, stream>>>(ei, et, bmS, sid, deg1);
    l1_chunk<<<NCH1, 256, 0, stream>>>(deg1, c1);
    l1_scan<<<1, 256, 0, stream>>>(c1, o1);
    l1_write<<<NCH1, 256, 0, stream>>>(deg1, o1, offs6s, cur1, spack1);
    l1_scatter<<<NBE, 256, 0, stream>>>(ei, et, bmS, sid, cur1, spack1);

    // layer 1 over |S| rows: aggregate-first from xh, then pipelined GEMM
    agg_s<<<MAXS / 4, 256, 0, stream>>>(cnts, offs6s, spack1, (const u32*)xh, A1s);
    gemm_lds3<<<MAXS / 128, 256, 0, stream>>>(A1s, xh, snode, Bt1, b1,
                                              (void*)h1s, cnts, 0, 1, 1);

    // layer 2 (2048 query rows)
    agg_q2<<<(2 * NQ + 3) / 4, 256, 0, stream>>>(offs2, spack2, (const u32*)h1s,
                                                 nest, food, tidm, sid, A2, sidq);
    gemm_lds3<<<(2 * NQ) / 128, 256, 0, stream>>>(A2, h1s, sidq, Bt2, b2,
                                                  (void*)h2q, nullptr, 2 * NQ, 0, 0);
    fc_kernel<<<NQ, 256, 0, stream>>>(h2q, Wfc, bfc, out);
}